// Round 1
// baseline (372.173 us; speedup 1.0000x reference)
//
#include <hip/hip_runtime.h>

// ContrastiveLoss fused: normalize -> bf16 MFMA GEMM (A @ B^T) with fused
// mask/row-reduce epilogue -> final scalar reduce.
// N=8192 rows, D=1024, n_classes=1024. Output: single f32 scalar.

constexpr int N = 8192;
constexpr int D = 1024;

typedef short bf16x8 __attribute__((ext_vector_type(8)));
typedef float f32x4 __attribute__((ext_vector_type(4)));

// RNE float->bf16 (finite inputs only)
static __device__ inline unsigned short f2bf(float f) {
  unsigned int u = __float_as_uint(f);
  unsigned int r = (u + 0x7fffu + ((u >> 16) & 1u)) >> 16;
  return (unsigned short)r;
}

// ---------------- normalize: fp32 row -> L2-normalized bf16 row -------------
__global__ __launch_bounds__(256) void normalize_kernel(
    const float* __restrict__ in_col, const float* __restrict__ in_row,
    unsigned short* __restrict__ out_col, unsigned short* __restrict__ out_row) {
  int row = blockIdx.x;
  const float* in;
  unsigned short* out;
  if (row < N) {
    in = in_col + (size_t)row * D;
    out = out_col + (size_t)row * D;
  } else {
    in = in_row + (size_t)(row - N) * D;
    out = out_row + (size_t)(row - N) * D;
  }
  int tid = threadIdx.x;
  float4 v = ((const float4*)in)[tid];  // 256 threads x 4 floats = 1024
  float s = v.x * v.x + v.y * v.y + v.z * v.z + v.w * v.w;
#pragma unroll
  for (int off = 32; off >= 1; off >>= 1) s += __shfl_xor(s, off, 64);
  __shared__ float wsum[4];
  int lane = tid & 63, wid = tid >> 6;
  if (lane == 0) wsum[wid] = s;
  __syncthreads();
  float tot = wsum[0] + wsum[1] + wsum[2] + wsum[3];
  float inv = 1.0f / sqrtf(tot + 1e-12f);  // matches x / sqrt(sum + 1e-12)
  ushort4 o;
  o.x = f2bf(v.x * inv);
  o.y = f2bf(v.y * inv);
  o.z = f2bf(v.z * inv);
  o.w = f2bf(v.w * inv);
  ((ushort4*)out)[tid] = o;
}

// ---------------- fused GEMM + loss epilogue --------------------------------
// Block: 256 thr = 4 waves (2x2). Tile 128x128, BK=32. LDS A[128][32], B[128][32].
__global__ __launch_bounds__(256) void loss_kernel(
    const unsigned short* __restrict__ An,  // normalized inputs_col [N][D] bf16
    const unsigned short* __restrict__ Bn,  // normalized inputs_row [N][D] bf16
    const int* __restrict__ tc, const int* __restrict__ tr,
    float* __restrict__ posG, float* __restrict__ negG, int* __restrict__ hasG) {
  __shared__ unsigned short As[128 * 32];
  __shared__ unsigned short Bs[128 * 32];

  const int tid = threadIdx.x;
  const int lane = tid & 63;
  const int wid = tid >> 6;
  const int wr = wid >> 1;   // wave row (0..1), owns 64 rows
  const int wc = wid & 1;    // wave col (0..1), owns 64 cols
  const int iBase = blockIdx.y * 128;
  const int jBase = blockIdx.x * 128;

  f32x4 acc[4][4];
#pragma unroll
  for (int mi = 0; mi < 4; mi++)
#pragma unroll
    for (int ni = 0; ni < 4; ni++) acc[mi][ni] = (f32x4){0.f, 0.f, 0.f, 0.f};

  // staging: thread t loads 16B: row = t/4 (+64 for 2nd call), col = (t%4)*8 elems
  const int srow = tid >> 2;
  const int scol = (tid & 3) * 8;
  const unsigned short* aSrc0 = An + (size_t)(iBase + srow) * D + scol;
  const unsigned short* aSrc1 = An + (size_t)(iBase + srow + 64) * D + scol;
  const unsigned short* bSrc0 = Bn + (size_t)(jBase + srow) * D + scol;
  const unsigned short* bSrc1 = Bn + (size_t)(jBase + srow + 64) * D + scol;
  // wave-uniform LDS dests: HW writes base + lane*16B
  unsigned short* aDst0 = As + wid * 512;         // bytes: wid*1024
  unsigned short* aDst1 = As + 2048 + wid * 512;  // +4096B
  unsigned short* bDst0 = Bs + wid * 512;
  unsigned short* bDst1 = Bs + 2048 + wid * 512;

  const int frow = lane & 15;       // fragment non-K index
  const int fk = (lane >> 4) * 8;   // fragment K base (elements)

#define GLDS(g, l)                                                         \
  __builtin_amdgcn_global_load_lds(                                        \
      (const __attribute__((address_space(1))) void*)(g),                  \
      (__attribute__((address_space(3))) void*)(l), 16, 0, 0)

  for (int kt = 0; kt < D / 32; ++kt) {
    const int ko = kt * 32;
    GLDS(aSrc0 + ko, aDst0);
    GLDS(aSrc1 + ko, aDst1);
    GLDS(bSrc0 + ko, bDst0);
    GLDS(bSrc1 + ko, bDst1);
    __syncthreads();  // compiler emits s_waitcnt vmcnt(0) before s_barrier

    bf16x8 af[4], bf[4];
#pragma unroll
    for (int mi = 0; mi < 4; mi++)
      af[mi] = *(const bf16x8*)(As + (wr * 64 + mi * 16 + frow) * 32 + fk);
#pragma unroll
    for (int ni = 0; ni < 4; ni++)
      bf[ni] = *(const bf16x8*)(Bs + (wc * 64 + ni * 16 + frow) * 32 + fk);
#pragma unroll
    for (int mi = 0; mi < 4; mi++)
#pragma unroll
      for (int ni = 0; ni < 4; ni++)
        acc[mi][ni] = __builtin_amdgcn_mfma_f32_16x16x32_bf16(
            af[mi], bf[ni], acc[mi][ni], 0, 0, 0);
    __syncthreads();  // protect LDS before next stage overwrites
  }
#undef GLDS

  // ---- epilogue: mask + per-row partial reduce + sparse atomics ----
  // C/D layout (m89/m91): row = (lane>>4)*4 + reg, col = lane&15
  int trj[4];
#pragma unroll
  for (int ni = 0; ni < 4; ni++) trj[ni] = tr[jBase + wc * 64 + ni * 16 + frow];

#pragma unroll
  for (int mi = 0; mi < 4; mi++) {
#pragma unroll
    for (int r = 0; r < 4; r++) {
      const int i = iBase + wr * 64 + mi * 16 + (lane >> 4) * 4 + r;
      const int tci = tc[i];
      float pos = 0.f, neg = 0.f;
      int cnt = 0;
#pragma unroll
      for (int ni = 0; ni < 4; ni++) {
        float s = acc[mi][ni][r];
        if (tci == trj[ni]) {
          if (s < 1.0f - 1e-5f) { pos += 1.0f - s; cnt++; }
        } else if (s > 0.5f) {
          neg += s;
        }
      }
      // reduce across the 16 lanes sharing this output row
#pragma unroll
      for (int off = 1; off < 16; off <<= 1) {
        pos += __shfl_xor(pos, off, 16);
        neg += __shfl_xor(neg, off, 16);
        cnt += __shfl_xor(cnt, off, 16);
      }
      if ((lane & 15) == 0) {
        if (cnt > 0) {
          atomicAdd(&posG[i], pos);
          atomicOr(&hasG[i], 1);
        }
        if (neg != 0.f) atomicAdd(&negG[i], neg);
      }
    }
  }
}

// ---------------- final scalar reduce ---------------------------------------
__global__ __launch_bounds__(256) void finalize_kernel(
    const float* __restrict__ posG, const float* __restrict__ negG,
    const int* __restrict__ hasG, float* __restrict__ out) {
  int tid = threadIdx.x;
  float s = 0.f;
  for (int i = tid; i < N; i += 256)
    if (hasG[i]) s += posG[i] + negG[i];
#pragma unroll
  for (int off = 32; off >= 1; off >>= 1) s += __shfl_xor(s, off, 64);
  __shared__ float w4[4];
  if ((tid & 63) == 0) w4[tid >> 6] = s;
  __syncthreads();
  if (tid == 0) out[0] = (w4[0] + w4[1] + w4[2] + w4[3]) / (float)N;
}

extern "C" void kernel_launch(void* const* d_in, const int* in_sizes, int n_in,
                              void* d_out, int out_size, void* d_ws, size_t ws_size,
                              hipStream_t stream) {
  const float* in_col = (const float*)d_in[0];
  const int* tcol = (const int*)d_in[1];
  const float* in_row = (const float*)d_in[2];
  const int* trow = (const int*)d_in[3];
  float* out = (float*)d_out;

  char* ws = (char*)d_ws;
  float* posG = (float*)ws;                 // N floats
  float* negG = (float*)(ws + (size_t)N * 4);  // N floats
  int* hasG = (int*)(ws + (size_t)N * 8);      // N ints
  unsigned short* colN = (unsigned short*)(ws + (size_t)N * 12);
  unsigned short* rowN = colN + (size_t)N * D;

  hipMemsetAsync(ws, 0, (size_t)N * 12, stream);
  normalize_kernel<<<2 * N, 256, 0, stream>>>(in_col, in_row, colN, rowN);
  dim3 grid(N / 128, N / 128);
  loss_kernel<<<grid, 256, 0, stream>>>(colN, rowN, tcol, trow, posG, negG, hasG);
  finalize_kernel<<<1, 256, 0, stream>>>(posG, negG, hasG, out);
}

// Round 2
// 309.584 us; speedup vs baseline: 1.2022x; 1.2022x over previous
//
#include <hip/hip_runtime.h>

// ContrastiveLoss: normalize -> 256x256 8-phase bf16 MFMA GEMM (A @ B^T) with
// fused mask/row-reduce epilogue -> final scalar reduce.
// N=8192, D=1024. Output: single f32 scalar.

constexpr int N = 8192;
constexpr int D = 1024;
constexpr int NT = D / 64;  // 16 K-tiles of BK=64

typedef short bf16x8 __attribute__((ext_vector_type(8)));
typedef float f32x4 __attribute__((ext_vector_type(4)));

static __device__ inline unsigned short f2bf(float f) {
  unsigned int u = __float_as_uint(f);
  unsigned int r = (u + 0x7fffu + ((u >> 16) & 1u)) >> 16;
  return (unsigned short)r;
}

// ---------------- normalize: fp32 row -> L2-normalized bf16 row -------------
__global__ __launch_bounds__(256) void normalize_kernel(
    const float* __restrict__ in_col, const float* __restrict__ in_row,
    unsigned short* __restrict__ out_col, unsigned short* __restrict__ out_row) {
  int row = blockIdx.x;
  const float* in;
  unsigned short* out;
  if (row < N) {
    in = in_col + (size_t)row * D;
    out = out_col + (size_t)row * D;
  } else {
    in = in_row + (size_t)(row - N) * D;
    out = out_row + (size_t)(row - N) * D;
  }
  int tid = threadIdx.x;
  float4 v = ((const float4*)in)[tid];
  float s = v.x * v.x + v.y * v.y + v.z * v.z + v.w * v.w;
#pragma unroll
  for (int off = 32; off >= 1; off >>= 1) s += __shfl_xor(s, off, 64);
  __shared__ float wsum[4];
  int lane = tid & 63, wid = tid >> 6;
  if (lane == 0) wsum[wid] = s;
  __syncthreads();
  float tot = wsum[0] + wsum[1] + wsum[2] + wsum[3];
  float inv = 1.0f / sqrtf(tot + 1e-12f);
  ushort4 o;
  o.x = f2bf(v.x * inv);
  o.y = f2bf(v.y * inv);
  o.z = f2bf(v.z * inv);
  o.w = f2bf(v.w * inv);
  ((ushort4*)out)[tid] = o;
}

// ---------------- fused 8-phase GEMM + loss epilogue ------------------------
// 512 thr = 8 waves (2 wave-rows x 4 wave-cols). Tile 256x256, BK=64.
// LDS: A [2dbuf][2half][128 r][64 k] + B same = 128 KiB, XOR-swizzled (T2).
__global__ __launch_bounds__(512, 2) void loss_kernel(
    const unsigned short* __restrict__ An, const unsigned short* __restrict__ Bn,
    const int* __restrict__ tc, const int* __restrict__ tr,
    float* __restrict__ lossG, int* __restrict__ hasG) {
  __shared__ unsigned short lds[65536];  // 128 KiB: A [0,32768) elems, B [32768,65536)

  const int tid = threadIdx.x;
  const int lane = tid & 63;
  const int wid = tid >> 6;
  const int wr = wid >> 2;  // 0..1 (owns 128 rows)
  const int wc = wid & 3;   // 0..3 (owns 64 cols)

  // XCD-aware swizzle (1024 blocks, 1024%8==0 -> simple form bijective)
  const int bid = blockIdx.x;
  const int swz = (bid & 7) * 128 + (bid >> 3);
  const int iBase = (swz >> 5) * 256;
  const int jBase = (swz & 31) * 256;

  // fragment addressing (reads are T2-swizzled)
  const int frow = lane & 15;
  const int fkb = (lane >> 4) * 16;        // K byte offset within 64B k-chunk pair
  const int rxor = (lane & 7) << 4;        // T2 swizzle mask
  const int kx0 = (0 + fkb) ^ rxor;        // kk=0
  const int kx1 = (64 + fkb) ^ rxor;       // kk=1
  int rowA[4], rowB[2];
#pragma unroll
  for (int m2 = 0; m2 < 4; m2++) rowA[m2] = (wr * 64 + m2 * 16 + frow) * 128;
#pragma unroll
  for (int n2 = 0; n2 < 2; n2++) rowB[n2] = (wc * 32 + n2 * 16 + frow) * 128;

  // staging addressing: thread handles local row rl, k-chunk kel (x2 rounds)
  const int rl0 = tid >> 3;                 // 0..63 (round 0), +64 (round 1)
  const int kel = (tid & 7) * 8;            // element k within BK
  const int kSw = kel ^ ((rl0 & 7) << 3);   // inverse-swizzled source k
  const int rA0 = iBase + rl0;              // global A row (round 0, +h*64)
  const int rB0 = jBase + ((rl0 >> 5) * 64) + (rl0 & 31);  // global B row

#define GLDS(g, l)                                                        \
  __builtin_amdgcn_global_load_lds(                                       \
      (const __attribute__((address_space(1))) void*)(g),                 \
      (__attribute__((address_space(3))) void*)(l), 16, 0, 0)

  // stage half-tile (A or B, half h) of K-tile tt; wrap tail (tt&15) to keep
  // vmcnt counting uniform (skipping would under-drain at the tail -> race)
#define STAGE_A(h, tt)                                                          \
  do {                                                                          \
    const int _k = ((tt) & 15) * 64 + kSw;                                      \
    unsigned short* _d = lds + ((((tt) & 1) * 2 + (h)) * 8192) + wid * 512;     \
    GLDS(An + (size_t)(rA0 + (h) * 64) * D + _k, _d);                           \
    GLDS(An + (size_t)(rA0 + 128 + (h) * 64) * D + _k, _d + 4096);              \
  } while (0)
#define STAGE_B(h, tt)                                                          \
  do {                                                                          \
    const int _k = ((tt) & 15) * 64 + kSw;                                      \
    unsigned short* _d = lds + 32768 + ((((tt) & 1) * 2 + (h)) * 8192) + wid * 512; \
    GLDS(Bn + (size_t)(rB0 + (h) * 32) * D + _k, _d);                           \
    GLDS(Bn + (size_t)(rB0 + 128 + (h) * 32) * D + _k, _d + 4096);              \
  } while (0)

  f32x4 acc[8][4];
#pragma unroll
  for (int mi = 0; mi < 8; mi++)
#pragma unroll
    for (int ni = 0; ni < 4; ni++) acc[mi][ni] = (f32x4){0.f, 0.f, 0.f, 0.f};

  bf16x8 af[4][2], bf[2][2];
  const char* ldsc = (const char*)lds;

  // prologue: 5 half-tiles; vmcnt(6) leaves the 3 newest in flight
  STAGE_A(0, 0);
  STAGE_B(0, 0);
  STAGE_B(1, 0);
  STAGE_A(1, 0);
  STAGE_A(0, 1);
  asm volatile("s_waitcnt vmcnt(6)" ::: "memory");
  __builtin_amdgcn_sched_barrier(0);
  __builtin_amdgcn_s_barrier();

#define PHASE(MIH, NIH, LOADA, STG)                                             \
  do {                                                                          \
    if (LOADA) {                                                                \
      _Pragma("unroll") for (int m2 = 0; m2 < 4; m2++) {                        \
        af[m2][0] = *(const bf16x8*)(ldsc + dA + (MIH) * 16384 + rowA[m2] + kx0); \
        af[m2][1] = *(const bf16x8*)(ldsc + dA + (MIH) * 16384 + rowA[m2] + kx1); \
      }                                                                         \
    }                                                                           \
    _Pragma("unroll") for (int n2 = 0; n2 < 2; n2++) {                          \
      bf[n2][0] = *(const bf16x8*)(ldsc + dB + (NIH) * 16384 + rowB[n2] + kx0);  \
      bf[n2][1] = *(const bf16x8*)(ldsc + dB + (NIH) * 16384 + rowB[n2] + kx1);  \
    }                                                                           \
    STG;                                                                        \
    __builtin_amdgcn_s_barrier();                                               \
    asm volatile("s_waitcnt lgkmcnt(0)");                                       \
    __builtin_amdgcn_sched_barrier(0);                                          \
    __builtin_amdgcn_s_setprio(1);                                              \
    _Pragma("unroll") for (int m2 = 0; m2 < 4; m2++)                            \
        _Pragma("unroll") for (int n2 = 0; n2 < 2; n2++)                        \
            _Pragma("unroll") for (int kk = 0; kk < 2; kk++)                    \
                acc[(MIH) * 4 + m2][(NIH) * 2 + n2] =                           \
                    __builtin_amdgcn_mfma_f32_16x16x32_bf16(                    \
                        af[m2][kk], bf[n2][kk],                                 \
                        acc[(MIH) * 4 + m2][(NIH) * 2 + n2], 0, 0, 0);          \
    __builtin_amdgcn_s_setprio(0);                                              \
    asm volatile("s_waitcnt vmcnt(6)" ::: "memory");                            \
    __builtin_amdgcn_sched_barrier(0);                                          \
    __builtin_amdgcn_s_barrier();                                               \
  } while (0)

  for (int t = 0; t < NT; ++t) {
    const int dA = (t & 1) * 32768;          // bytes: dbuf base in A region
    const int dB = 65536 + (t & 1) * 32768;  // bytes: dbuf base in B region
    PHASE(0, 0, true, STAGE_B(0, t + 1));
    PHASE(0, 1, false, STAGE_B(1, t + 1));
    PHASE(1, 0, true, STAGE_A(1, t + 1));
    PHASE(1, 1, false, STAGE_A(0, t + 2));
  }
#undef PHASE
#undef STAGE_A
#undef STAGE_B
#undef GLDS

  // ---- epilogue: mask + per-row reduce + sparse atomics ----
  // C/D layout: col = lane&15, row = (lane>>4)*4 + reg
  int trj[4];
#pragma unroll
  for (int ni = 0; ni < 4; ni++) trj[ni] = tr[jBase + wc * 64 + ni * 16 + frow];

#pragma unroll
  for (int mi = 0; mi < 8; mi++) {
#pragma unroll
    for (int r = 0; r < 4; r++) {
      const int i = iBase + wr * 128 + mi * 16 + (lane >> 4) * 4 + r;
      const int tci = tc[i];
      float v = 0.f;
      bool hasp = false;
#pragma unroll
      for (int ni = 0; ni < 4; ni++) {
        float s = acc[mi][ni][r];
        if (tci == trj[ni]) {
          if (s < 1.0f - 1e-5f) { v += 1.0f - s; hasp = true; }
        } else if (s > 0.5f) {
          v += s;
        }
      }
#pragma unroll
      for (int off = 1; off < 16; off <<= 1) v += __shfl_xor(v, off, 16);
      unsigned long long m = __ballot(hasp);
      bool rowHas = ((m >> ((lane >> 4) * 16)) & 0xFFFFull) != 0;
      if ((lane & 15) == 0) {
        if (v != 0.f) atomicAdd(&lossG[i], v);
        if (rowHas) atomicOr(&hasG[i], 1);
      }
    }
  }
}

// ---------------- final scalar reduce ---------------------------------------
__global__ __launch_bounds__(256) void finalize_kernel(
    const float* __restrict__ lossG, const int* __restrict__ hasG,
    float* __restrict__ out) {
  int tid = threadIdx.x;
  float s = 0.f;
  for (int i = tid; i < N; i += 256)
    if (hasG[i]) s += lossG[i];
#pragma unroll
  for (int off = 32; off >= 1; off >>= 1) s += __shfl_xor(s, off, 64);
  __shared__ float w4[4];
  if ((tid & 63) == 0) w4[tid >> 6] = s;
  __syncthreads();
  if (tid == 0) out[0] = (w4[0] + w4[1] + w4[2] + w4[3]) / (float)N;
}

extern "C" void kernel_launch(void* const* d_in, const int* in_sizes, int n_in,
                              void* d_out, int out_size, void* d_ws, size_t ws_size,
                              hipStream_t stream) {
  const float* in_col = (const float*)d_in[0];
  const int* tcol = (const int*)d_in[1];
  const float* in_row = (const float*)d_in[2];
  const int* trow = (const int*)d_in[3];
  float* out = (float*)d_out;

  char* ws = (char*)d_ws;
  float* lossG = (float*)ws;                      // N floats
  int* hasG = (int*)(ws + (size_t)N * 4);         // N ints
  unsigned short* colN = (unsigned short*)(ws + (size_t)N * 8);
  unsigned short* rowN = colN + (size_t)N * D;

  hipMemsetAsync(ws, 0, (size_t)N * 8, stream);
  normalize_kernel<<<2 * N, 256, 0, stream>>>(in_col, in_row, colN, rowN);
  loss_kernel<<<1024, 512, 0, stream>>>(colN, rowN, tcol, trow, lossG, hasG);
  finalize_kernel<<<1, 256, 0, stream>>>(lossG, hasG, out);
}

// Round 3
// 297.847 us; speedup vs baseline: 1.2495x; 1.0394x over previous
//
#include <hip/hip_runtime.h>

// ContrastiveLoss: normalize -> 256x256 8-phase bf16 MFMA GEMM (A @ B^T) with
// fused mask/row-reduce epilogue -> final scalar reduce.
// N=8192, D=1024. Output: single f32 scalar.

constexpr int N = 8192;
constexpr int D = 1024;
constexpr int NT = D / 64;  // 16 K-tiles of BK=64

typedef short bf16x8 __attribute__((ext_vector_type(8)));
typedef float f32x4 __attribute__((ext_vector_type(4)));

static __device__ inline unsigned short f2bf(float f) {
  unsigned int u = __float_as_uint(f);
  unsigned int r = (u + 0x7fffu + ((u >> 16) & 1u)) >> 16;
  return (unsigned short)r;
}

// ---------------- normalize: fp32 row -> L2-normalized bf16 row -------------
__global__ __launch_bounds__(256) void normalize_kernel(
    const float* __restrict__ in_col, const float* __restrict__ in_row,
    unsigned short* __restrict__ out_col, unsigned short* __restrict__ out_row) {
  int row = blockIdx.x;
  const float* in;
  unsigned short* out;
  if (row < N) {
    in = in_col + (size_t)row * D;
    out = out_col + (size_t)row * D;
  } else {
    in = in_row + (size_t)(row - N) * D;
    out = out_row + (size_t)(row - N) * D;
  }
  int tid = threadIdx.x;
  float4 v = ((const float4*)in)[tid];
  float s = v.x * v.x + v.y * v.y + v.z * v.z + v.w * v.w;
#pragma unroll
  for (int off = 32; off >= 1; off >>= 1) s += __shfl_xor(s, off, 64);
  __shared__ float wsum[4];
  int lane = tid & 63, wid = tid >> 6;
  if (lane == 0) wsum[wid] = s;
  __syncthreads();
  float tot = wsum[0] + wsum[1] + wsum[2] + wsum[3];
  float inv = 1.0f / sqrtf(tot + 1e-12f);
  ushort4 o;
  o.x = f2bf(v.x * inv);
  o.y = f2bf(v.y * inv);
  o.z = f2bf(v.z * inv);
  o.w = f2bf(v.w * inv);
  ((ushort4*)out)[tid] = o;
}

// ---------------- fused 8-phase GEMM + loss epilogue ------------------------
// 512 thr = 8 waves (2 wave-rows x 4 wave-cols). Tile 256x256, BK=64.
// LDS: A [2dbuf][2half][128 r][64 k] + B same = 128 KiB, XOR-swizzled (T2).
// Gray-code phase order (0,0)->(0,1)->(1,1)->(1,0): B frags retained across
// the middle seam (28 ds_read_b128 / K-tile). One counted vmcnt(2) per K-tile.
__global__ __launch_bounds__(512, 2) void loss_kernel(
    const unsigned short* __restrict__ An, const unsigned short* __restrict__ Bn,
    const int* __restrict__ tc, const int* __restrict__ tr,
    float* __restrict__ lossG, int* __restrict__ hasG) {
  __shared__ unsigned short lds[65536];  // 128 KiB: A elems [0,32768), B [32768,65536)

  const int tid = threadIdx.x;
  const int lane = tid & 63;
  const int wid = tid >> 6;
  const int wr = wid >> 2;  // 0..1 (owns 128 rows)
  const int wc = wid & 3;   // 0..3 (owns 64 cols)

  // XCD-aware 2D swizzle: XCD x = bid&7 owns j-panels [4x, 4x+4); resident-32
  // per XCD = 8i x 4j patch -> B (2 MB) stays L2-pinned per XCD.
  const int bid = blockIdx.x;
  const int x = bid & 7, s = bid >> 3;
  const int iBase = (((s & 7) | ((s >> 5) << 3))) * 256;
  const int jBase = (x * 4 + ((s >> 3) & 3)) * 256;

  // fragment addressing (reads are T2-swizzled)
  const int frow = lane & 15;
  const int fkb = (lane >> 4) * 16;   // K byte offset within 64B k-chunk
  const int rxor = (lane & 7) << 4;   // T2 swizzle mask
  const int kx0 = (0 + fkb) ^ rxor;   // kk=0
  const int kx1 = (64 + fkb) ^ rxor;  // kk=1
  int rowA[4], rowB[2];
#pragma unroll
  for (int m2 = 0; m2 < 4; m2++) rowA[m2] = (wr * 64 + m2 * 16 + frow) * 128;
#pragma unroll
  for (int n2 = 0; n2 < 2; n2++) rowB[n2] = (wc * 32 + n2 * 16 + frow) * 128;

  // staging addressing: thread handles local row rl0, k-chunk kel
  const int rl0 = tid >> 3;                // 0..63
  const int kel = (tid & 7) * 8;           // element k within BK
  const int kSw = kel ^ ((rl0 & 7) << 3);  // inverse-swizzled source k
  const int rA0 = iBase + rl0;
  const int rB0 = jBase + ((rl0 >> 5) * 64) + (rl0 & 31);

#define GLDS(g, l)                                                        \
  __builtin_amdgcn_global_load_lds(                                       \
      (const __attribute__((address_space(1))) void*)(g),                 \
      (__attribute__((address_space(3))) void*)(l), 16, 0, 0)

  // stage half-tile of K-tile tt into dbuf parity P (literal). Wrap tail
  // (tt&15) to keep vmcnt counting uniform.
#define STAGE_A(h, tt, P)                                                     \
  do {                                                                        \
    const int _k = ((tt) & 15) * 64 + kSw;                                    \
    unsigned short* _d = lds + (((P) * 2 + (h)) * 8192) + wid * 512;          \
    GLDS(An + (size_t)(rA0 + (h) * 64) * D + _k, _d);                         \
    GLDS(An + (size_t)(rA0 + 128 + (h) * 64) * D + _k, _d + 4096);            \
  } while (0)
#define STAGE_B(h, tt, P)                                                     \
  do {                                                                        \
    const int _k = ((tt) & 15) * 64 + kSw;                                    \
    unsigned short* _d = lds + 32768 + (((P) * 2 + (h)) * 8192) + wid * 512;  \
    GLDS(Bn + (size_t)(rB0 + (h) * 32) * D + _k, _d);                         \
    GLDS(Bn + (size_t)(rB0 + 128 + (h) * 32) * D + _k, _d + 4096);            \
  } while (0)

  f32x4 acc[8][4];
#pragma unroll
  for (int mi = 0; mi < 8; mi++)
#pragma unroll
    for (int ni = 0; ni < 4; ni++) acc[mi][ni] = (f32x4){0.f, 0.f, 0.f, 0.f};

  bf16x8 af[4][2], bf[2][2];
  const char* ldsc = (const char*)lds;

  // prologue: tile0's 4 halves + A1(1); drain first 8 loads, leave 2 in flight
  STAGE_A(0, 0, 0);
  STAGE_B(0, 0, 0);
  STAGE_B(1, 0, 0);
  STAGE_A(1, 0, 0);
  STAGE_A(1, 1, 1);
  asm volatile("s_waitcnt vmcnt(2)" ::: "memory");
  __builtin_amdgcn_s_barrier();

  // Phase: ds_read frags || stage -> barrier -> lgkm(0) -> 16 MFMA -> [drain]
  // -> barrier. No sched_barrier pins: compiler-visible ds_reads carry their
  // own deps; memory-clobber asm fences block load motion across barriers.
#define PH(MIH, NIH, LOADA, LOADB, DA, DB, STG, DRN)                            \
  do {                                                                          \
    if (LOADA) {                                                                \
      _Pragma("unroll") for (int m2 = 0; m2 < 4; m2++) {                        \
        af[m2][0] = *(const bf16x8*)(ldsc + (DA) + (MIH) * 16384 + rowA[m2] + kx0); \
        af[m2][1] = *(const bf16x8*)(ldsc + (DA) + (MIH) * 16384 + rowA[m2] + kx1); \
      }                                                                         \
    }                                                                           \
    if (LOADB) {                                                                \
      _Pragma("unroll") for (int n2 = 0; n2 < 2; n2++) {                        \
        bf[n2][0] = *(const bf16x8*)(ldsc + (DB) + (NIH) * 16384 + rowB[n2] + kx0); \
        bf[n2][1] = *(const bf16x8*)(ldsc + (DB) + (NIH) * 16384 + rowB[n2] + kx1); \
      }                                                                         \
    }                                                                           \
    STG;                                                                        \
    asm volatile("" ::: "memory");                                              \
    __builtin_amdgcn_s_barrier();                                               \
    asm volatile("s_waitcnt lgkmcnt(0)" ::: "memory");                          \
    __builtin_amdgcn_s_setprio(1);                                              \
    _Pragma("unroll") for (int m2 = 0; m2 < 4; m2++)                            \
        _Pragma("unroll") for (int n2 = 0; n2 < 2; n2++)                        \
            _Pragma("unroll") for (int kk = 0; kk < 2; kk++)                    \
                acc[(MIH) * 4 + m2][(NIH) * 2 + n2] =                           \
                    __builtin_amdgcn_mfma_f32_16x16x32_bf16(                    \
                        af[m2][kk], bf[n2][kk],                                 \
                        acc[(MIH) * 4 + m2][(NIH) * 2 + n2], 0, 0, 0);          \
    __builtin_amdgcn_s_setprio(0);                                              \
    DRN;                                                                        \
    asm volatile("" ::: "memory");                                              \
    __builtin_amdgcn_s_barrier();                                               \
  } while (0)

#define DRAIN asm volatile("s_waitcnt vmcnt(2)" ::: "memory")

  // Per tile T (parity P): Gray order; stage A0/B0/B1 of T+1 (parity 1-P) at
  // P1-P3, A1 of T+2 (parity P, region dead after this tile's P3) at P4.
#define TILE(T, P)                                                              \
  do {                                                                          \
    PH(0, 0, true, true, (P)*32768, 65536 + (P)*32768,                          \
       STAGE_A(0, (T) + 1, 1 - (P)), );                                         \
    PH(0, 1, false, true, (P)*32768, 65536 + (P)*32768,                         \
       STAGE_B(0, (T) + 1, 1 - (P)), );                                         \
    PH(1, 1, true, false, (P)*32768, 65536 + (P)*32768,                         \
       STAGE_B(1, (T) + 1, 1 - (P)), );                                         \
    PH(1, 0, false, true, (P)*32768, 65536 + (P)*32768,                         \
       STAGE_A(1, (T) + 2, (P)), DRAIN);                                        \
  } while (0)

  for (int tp = 0; tp < NT / 2; ++tp) {
    const int t0 = 2 * tp;
    TILE(t0, 0);
    TILE(t0 + 1, 1);
  }
  asm volatile("s_waitcnt vmcnt(0)" ::: "memory");
#undef TILE
#undef PH
#undef DRAIN
#undef STAGE_A
#undef STAGE_B
#undef GLDS

  // ---- epilogue: mask + per-row reduce + sparse atomics ----
  // C/D layout: col = lane&15, row = (lane>>4)*4 + reg
  int trj[4];
#pragma unroll
  for (int ni = 0; ni < 4; ni++) trj[ni] = tr[jBase + wc * 64 + ni * 16 + frow];

#pragma unroll
  for (int mi = 0; mi < 8; mi++) {
#pragma unroll
    for (int r = 0; r < 4; r++) {
      const int i = iBase + wr * 128 + mi * 16 + (lane >> 4) * 4 + r;
      const int tci = tc[i];
      float v = 0.f;
      bool hasp = false;
#pragma unroll
      for (int ni = 0; ni < 4; ni++) {
        float s2 = acc[mi][ni][r];
        if (tci == trj[ni]) {
          if (s2 < 1.0f - 1e-5f) { v += 1.0f - s2; hasp = true; }
        } else if (s2 > 0.5f) {
          v += s2;
        }
      }
#pragma unroll
      for (int off = 1; off < 16; off <<= 1) v += __shfl_xor(v, off, 16);
      unsigned long long m = __ballot(hasp);
      bool rowHas = ((m >> ((lane >> 4) * 16)) & 0xFFFFull) != 0;
      if ((lane & 15) == 0) {
        if (v != 0.f) atomicAdd(&lossG[i], v);
        if (rowHas) atomicOr(&hasG[i], 1);
      }
    }
  }
}

// ---------------- final scalar reduce ---------------------------------------
__global__ __launch_bounds__(256) void finalize_kernel(
    const float* __restrict__ lossG, const int* __restrict__ hasG,
    float* __restrict__ out) {
  int tid = threadIdx.x;
  float s = 0.f;
  for (int i = tid; i < N; i += 256)
    if (hasG[i]) s += lossG[i];
#pragma unroll
  for (int off = 32; off >= 1; off >>= 1) s += __shfl_xor(s, off, 64);
  __shared__ float w4[4];
  if ((tid & 63) == 0) w4[tid >> 6] = s;
  __syncthreads();
  if (tid == 0) out[0] = (w4[0] + w4[1] + w4[2] + w4[3]) / (float)N;
}

extern "C" void kernel_launch(void* const* d_in, const int* in_sizes, int n_in,
                              void* d_out, int out_size, void* d_ws, size_t ws_size,
                              hipStream_t stream) {
  const float* in_col = (const float*)d_in[0];
  const int* tcol = (const int*)d_in[1];
  const float* in_row = (const float*)d_in[2];
  const int* trow = (const int*)d_in[3];
  float* out = (float*)d_out;

  char* ws = (char*)d_ws;
  float* lossG = (float*)ws;               // N floats
  int* hasG = (int*)(ws + (size_t)N * 4);  // N ints
  unsigned short* colN = (unsigned short*)(ws + (size_t)N * 8);
  unsigned short* rowN = colN + (size_t)N * D;

  hipMemsetAsync(ws, 0, (size_t)N * 8, stream);
  normalize_kernel<<<2 * N, 256, 0, stream>>>(in_col, in_row, colN, rowN);
  loss_kernel<<<1024, 512, 0, stream>>>(colN, rowN, tcol, trow, lossG, hasG);
  finalize_kernel<<<1, 256, 0, stream>>>(lossG, hasG, out);
}

// Round 4
// 289.392 us; speedup vs baseline: 1.2861x; 1.0292x over previous
//
#include <hip/hip_runtime.h>

// ContrastiveLoss: normalize -> 256x256 8-phase bf16 MFMA GEMM (A @ B^T) with
// fused mask/row-reduce epilogue -> final scalar reduce.
// N=8192, D=1024. Output: single f32 scalar.

constexpr int N = 8192;
constexpr int D = 1024;
constexpr int NT = D / 64;  // 16 K-tiles of BK=64

typedef short bf16x8 __attribute__((ext_vector_type(8)));
typedef float f32x4 __attribute__((ext_vector_type(4)));

static __device__ inline unsigned short f2bf(float f) {
  unsigned int u = __float_as_uint(f);
  unsigned int r = (u + 0x7fffu + ((u >> 16) & 1u)) >> 16;
  return (unsigned short)r;
}

// ---------------- normalize: fp32 row -> L2-normalized bf16 row -------------
// One wave per row: no block barrier, 16 floats/lane.
__global__ __launch_bounds__(256) void normalize_kernel(
    const float* __restrict__ in_col, const float* __restrict__ in_row,
    unsigned short* __restrict__ out_col, unsigned short* __restrict__ out_row) {
  int r = blockIdx.x * 4 + (threadIdx.x >> 6);
  int lane = threadIdx.x & 63;
  const float* in =
      (r < N) ? in_col + (size_t)r * D : in_row + (size_t)(r - N) * D;
  unsigned short* out =
      (r < N) ? out_col + (size_t)r * D : out_row + (size_t)(r - N) * D;
  float4 v[4];
  float s = 0.f;
#pragma unroll
  for (int c = 0; c < 4; c++) {
    v[c] = ((const float4*)in)[lane + c * 64];
    s += v[c].x * v[c].x + v[c].y * v[c].y + v[c].z * v[c].z + v[c].w * v[c].w;
  }
#pragma unroll
  for (int off = 32; off >= 1; off >>= 1) s += __shfl_xor(s, off, 64);
  float inv = 1.0f / sqrtf(s + 1e-12f);
#pragma unroll
  for (int c = 0; c < 4; c++) {
    ushort4 o;
    o.x = f2bf(v[c].x * inv);
    o.y = f2bf(v[c].y * inv);
    o.z = f2bf(v[c].z * inv);
    o.w = f2bf(v[c].w * inv);
    ((ushort4*)out)[lane + c * 64] = o;
  }
}

// ---------------- fused GEMM + loss epilogue --------------------------------
// 512 thr = 8 waves (2 wave-rows x 4 wave-cols). Tile 256x256, BK=64.
// LDS: A [2dbuf][2half][128r][64k] + B same = 128 KiB, T2 XOR-swizzled.
// One barrier/phase: {reads_P, stage, [sync], BAR, prio1, MFMA_P, prio0}.
// Compiler inserts counted lgkmcnt between reads and MFMAs (no manual drain).
__global__ __launch_bounds__(512, 2) void loss_kernel(
    const unsigned short* __restrict__ An, const unsigned short* __restrict__ Bn,
    const int* __restrict__ tc, const int* __restrict__ tr,
    float* __restrict__ lossG, int* __restrict__ hasG) {
  __shared__ unsigned short lds[65536];  // A elems [0,32768), B [32768,65536)

  const int tid = threadIdx.x;
  const int lane = tid & 63;
  const int wid = tid >> 6;
  const int wr = wid >> 2;  // 0..1 (owns 128 rows)
  const int wc = wid & 3;   // 0..3 (owns 64 cols)

  // XCD-aware 2D swizzle: per-XCD resident-32 = 8i x 4j patch (B L2-pinned)
  const int bid = blockIdx.x;
  const int x = bid & 7, s = bid >> 3;
  const int iBase = (((s & 7) | ((s >> 5) << 3))) * 256;
  const int jBase = (x * 4 + ((s >> 3) & 3)) * 256;

  // fragment addressing (reads are T2-swizzled)
  const int frow = lane & 15;
  const int fkb = (lane >> 4) * 16;   // K byte offset within 64B k-chunk
  const int rxor = (lane & 7) << 4;   // T2 swizzle mask
  const int kx0 = (0 + fkb) ^ rxor;   // kk=0
  const int kx1 = (64 + fkb) ^ rxor;  // kk=1
  int rowA[4], rowB[2];
#pragma unroll
  for (int m2 = 0; m2 < 4; m2++) rowA[m2] = (wr * 64 + m2 * 16 + frow) * 128;
#pragma unroll
  for (int n2 = 0; n2 < 2; n2++) rowB[n2] = (wc * 32 + n2 * 16 + frow) * 128;

  // staging addressing
  const int rl0 = tid >> 3;                // 0..63
  const int kel = (tid & 7) * 8;           // element k within BK
  const int kSw = kel ^ ((rl0 & 7) << 3);  // inverse-swizzled source k
  const int rA0 = iBase + rl0;
  const int rB0 = jBase + ((rl0 >> 5) * 64) + (rl0 & 31);

#define GLDS(g, l)                                                        \
  __builtin_amdgcn_global_load_lds(                                       \
      (const __attribute__((address_space(1))) void*)(g),                 \
      (__attribute__((address_space(3))) void*)(l), 16, 0, 0)

#define STAGE_A(h, tt, P)                                                     \
  do {                                                                        \
    const int _k = ((tt) & 15) * 64 + kSw;                                    \
    unsigned short* _d = lds + (((P) * 2 + (h)) * 8192) + wid * 512;          \
    GLDS(An + (size_t)(rA0 + (h) * 64) * D + _k, _d);                         \
    GLDS(An + (size_t)(rA0 + 128 + (h) * 64) * D + _k, _d + 4096);            \
  } while (0)
#define STAGE_B(h, tt, P)                                                     \
  do {                                                                        \
    const int _k = ((tt) & 15) * 64 + kSw;                                    \
    unsigned short* _d = lds + 32768 + (((P) * 2 + (h)) * 8192) + wid * 512;  \
    GLDS(Bn + (size_t)(rB0 + (h) * 32) * D + _k, _d);                         \
    GLDS(Bn + (size_t)(rB0 + 128 + (h) * 32) * D + _k, _d + 4096);            \
  } while (0)

  f32x4 acc[8][4];
#pragma unroll
  for (int mi = 0; mi < 8; mi++)
#pragma unroll
    for (int ni = 0; ni < 4; ni++) acc[mi][ni] = (f32x4){0.f, 0.f, 0.f, 0.f};

  bf16x8 af[4][2], bf[2][2];
  const char* ldsc = (const char*)lds;

  // prologue: {A0,B0,B1,A1}(t0,b0) + A1(t1,b1); vmcnt(2) completes first 4
  STAGE_A(0, 0, 0);
  STAGE_B(0, 0, 0);
  STAGE_B(1, 0, 0);
  STAGE_A(1, 0, 0);
  STAGE_A(1, 1, 1);
  asm volatile("s_waitcnt vmcnt(2)" ::: "memory");
  __builtin_amdgcn_s_barrier();
  asm volatile("" ::: "memory");

  // PRE: 0=none, 1=lgkmcnt(0) harden (phase before the 1-phase-gap stage),
  //      2=vmcnt(2) per-tile drain
#define PH(MIH, NIH, LOADA, LOADB, DA, DB, STG, PRE)                            \
  do {                                                                          \
    if (LOADA) {                                                                \
      _Pragma("unroll") for (int m2 = 0; m2 < 4; m2++) {                        \
        af[m2][0] = *(const bf16x8*)(ldsc + (DA) + (MIH) * 16384 + rowA[m2] + kx0); \
        af[m2][1] = *(const bf16x8*)(ldsc + (DA) + (MIH) * 16384 + rowA[m2] + kx1); \
      }                                                                         \
    }                                                                           \
    if (LOADB) {                                                                \
      _Pragma("unroll") for (int n2 = 0; n2 < 2; n2++) {                        \
        bf[n2][0] = *(const bf16x8*)(ldsc + (DB) + (NIH) * 16384 + rowB[n2] + kx0); \
        bf[n2][1] = *(const bf16x8*)(ldsc + (DB) + (NIH) * 16384 + rowB[n2] + kx1); \
      }                                                                         \
    }                                                                           \
    STG;                                                                        \
    if ((PRE) == 1) asm volatile("s_waitcnt lgkmcnt(0)" ::: "memory");          \
    if ((PRE) == 2) asm volatile("s_waitcnt vmcnt(2)" ::: "memory");            \
    asm volatile("" ::: "memory");                                              \
    __builtin_amdgcn_s_barrier();                                               \
    asm volatile("" ::: "memory");                                              \
    __builtin_amdgcn_s_setprio(1);                                              \
    _Pragma("unroll") for (int kk = 0; kk < 2; kk++)                            \
        _Pragma("unroll") for (int m2 = 0; m2 < 4; m2++)                        \
            _Pragma("unroll") for (int n2 = 0; n2 < 2; n2++)                    \
                acc[(MIH) * 4 + m2][(NIH) * 2 + n2] =                           \
                    __builtin_amdgcn_mfma_f32_16x16x32_bf16(                    \
                        af[m2][kk], bf[n2][kk],                                 \
                        acc[(MIH) * 4 + m2][(NIH) * 2 + n2], 0, 0, 0);          \
    __builtin_amdgcn_s_setprio(0);                                              \
  } while (0)

  // Per tile T (parity P), Gray order (0,0)(0,1)(1,1)(1,0):
  // reads/phase = 12,4,8,4 (B0 re-read at P4); stages = R3-verified schedule.
#define TILE(T, P)                                                              \
  do {                                                                          \
    PH(0, 0, true, true, (P)*32768, 65536 + (P)*32768,                          \
       STAGE_A(0, (T) + 1, 1 - (P)), 0);                                        \
    PH(0, 1, false, true, (P)*32768, 65536 + (P)*32768,                         \
       STAGE_B(0, (T) + 1, 1 - (P)), 0);                                        \
    PH(1, 1, true, false, (P)*32768, 65536 + (P)*32768,                         \
       STAGE_B(1, (T) + 1, 1 - (P)), 1);                                        \
    PH(1, 0, false, true, (P)*32768, 65536 + (P)*32768,                         \
       STAGE_A(1, (T) + 2, (P)), 2);                                            \
  } while (0)

  for (int tp = 0; tp < NT / 2; ++tp) {
    const int t0 = 2 * tp;
    TILE(t0, 0);
    TILE(t0 + 1, 1);
  }
  asm volatile("s_waitcnt vmcnt(0)" ::: "memory");
#undef TILE
#undef PH
#undef STAGE_A
#undef STAGE_B
#undef GLDS

  // ---- epilogue: mask + per-row reduce + sparse atomics ----
  // C/D layout: col = lane&15, row = (lane>>4)*4 + reg
  int trj[4];
#pragma unroll
  for (int ni = 0; ni < 4; ni++) trj[ni] = tr[jBase + wc * 64 + ni * 16 + frow];

#pragma unroll
  for (int mi = 0; mi < 8; mi++) {
#pragma unroll
    for (int r = 0; r < 4; r++) {
      const int i = iBase + wr * 128 + mi * 16 + (lane >> 4) * 4 + r;
      const int tci = tc[i];
      float v = 0.f;
      bool hasp = false;
#pragma unroll
      for (int ni = 0; ni < 4; ni++) {
        float s2 = acc[mi][ni][r];
        if (tci == trj[ni]) {
          if (s2 < 1.0f - 1e-5f) { v += 1.0f - s2; hasp = true; }
        } else if (s2 > 0.5f) {
          v += s2;
        }
      }
#pragma unroll
      for (int off = 1; off < 16; off <<= 1) v += __shfl_xor(v, off, 16);
      unsigned long long m = __ballot(hasp);
      bool rowHas = ((m >> ((lane >> 4) * 16)) & 0xFFFFull) != 0;
      if ((lane & 15) == 0) {
        if (v != 0.f) atomicAdd(&lossG[i], v);
        if (rowHas) atomicOr(&hasG[i], 1);
      }
    }
  }
}

// ---------------- final scalar reduce ---------------------------------------
__global__ __launch_bounds__(256) void finalize_kernel(
    const float* __restrict__ lossG, const int* __restrict__ hasG,
    float* __restrict__ out) {
  int tid = threadIdx.x;
  float s = 0.f;
  for (int i = tid; i < N; i += 256)
    if (hasG[i]) s += lossG[i];
#pragma unroll
  for (int off = 32; off >= 1; off >>= 1) s += __shfl_xor(s, off, 64);
  __shared__ float w4[4];
  if ((tid & 63) == 0) w4[tid >> 6] = s;
  __syncthreads();
  if (tid == 0) out[0] = (w4[0] + w4[1] + w4[2] + w4[3]) / (float)N;
}

extern "C" void kernel_launch(void* const* d_in, const int* in_sizes, int n_in,
                              void* d_out, int out_size, void* d_ws, size_t ws_size,
                              hipStream_t stream) {
  const float* in_col = (const float*)d_in[0];
  const int* tcol = (const int*)d_in[1];
  const float* in_row = (const float*)d_in[2];
  const int* trow = (const int*)d_in[3];
  float* out = (float*)d_out;

  char* ws = (char*)d_ws;
  float* lossG = (float*)ws;               // N floats
  int* hasG = (int*)(ws + (size_t)N * 4);  // N ints
  unsigned short* colN = (unsigned short*)(ws + (size_t)N * 8);
  unsigned short* rowN = colN + (size_t)N * D;

  hipMemsetAsync(ws, 0, (size_t)N * 8, stream);
  normalize_kernel<<<(2 * N) / 4, 256, 0, stream>>>(in_col, in_row, colN, rowN);
  loss_kernel<<<1024, 512, 0, stream>>>(colN, rowN, tcol, trow, lossG, hasG);
  finalize_kernel<<<1, 256, 0, stream>>>(lossG, hasG, out);
}